// Round 4
// baseline (872.824 us; speedup 1.0000x reference)
//
#include <hip/hip_runtime.h>

#define NPOS (16*128*128)   // B*H*W = 262144
#define HWN  16384          // H*W

typedef float v2f __attribute__((ext_vector_type(2)));

// workspace float offsets
#define WS_WMUT  0          // [152][128] transposed Wmu (row r = input channel, col o = output)
#define WS_WSIGT 19456      // [152][8]   transposed Wsig
#define WS_WPI   20672      // [8][16]
#define WS_BPI   20800      // [8]
#define WS_BMU   20808      // [128]
#define WS_BSIG  20936      // [8]
#define WS_WG    20944      // [8]
#define WS_BG    20952      // [1]
#define WS_TOTAL 20953

__global__ __launch_bounds__(256) void prep_weights(
    const float* __restrict__ Wpi, const float* __restrict__ bpi,
    const float* __restrict__ Wmu, const float* __restrict__ bmu,
    const float* __restrict__ Wsig, const float* __restrict__ bsig,
    const float* __restrict__ Wg,  const float* __restrict__ bg,
    float* __restrict__ ws)
{
  int i = blockIdx.x*256 + threadIdx.x;
  if (i < 19456){ int c = i >> 7, o = i & 127; ws[WS_WMUT + i] = Wmu[o*152 + c]; return; }
  i -= 19456;
  if (i < 1216){ int c = i >> 3, j = i & 7; ws[WS_WSIGT + i] = Wsig[j*152 + c]; return; }
  i -= 1216;
  if (i < 128){ ws[WS_WPI + i] = Wpi[i]; return; }
  i -= 128;
  if (i < 8){ ws[WS_BPI + i] = bpi[i]; return; }
  i -= 8;
  if (i < 128){ ws[WS_BMU + i] = bmu[i]; return; }
  i -= 128;
  if (i < 8){ ws[WS_BSIG + i] = bsig[i]; return; }
  i -= 8;
  if (i < 8){ ws[WS_WG + i] = Wg[i]; return; }
  i -= 8;
  if (i < 1){ ws[WS_BG] = bg[0]; }
}

__device__ __forceinline__ v2f pkfma(v2f a, v2f b, v2f c){
#if __has_builtin(__builtin_elementwise_fma)
  return __builtin_elementwise_fma(a, b, c);
#else
  v2f r; r.x = __builtin_fmaf(a.x, b.x, c.x); r.y = __builtin_fmaf(a.y, b.y, c.y); return r;
#endif
}

// Each thread: 2 positions x 64 outputs (output half h is WAVE-uniform).
// Wave-level weight fetch = 152x64 floats (38.9 KB) instead of 152x128,
// while covering 2x positions per thread -> scalar (s_load) weight-broadcast
// traffic drops 4x (319 MB -> 80 MB total). k-loop rolled (hot body ~10 KB).
// Partner waves (w ^ 2, same lanes, same positions, other output half)
// exchange sigma mu-parts + dist2 halves through LDS at the end.
__global__ __launch_bounds__(256, 2) void gmm_fused(
    const float* __restrict__ x,
    const float* __restrict__ pi,
    const float* __restrict__ sigma,
    const float* __restrict__ mu,
    const float* __restrict__ ws,
    float* __restrict__ out)
{
  const int w  = threadIdx.x >> 6;   // wave 0..3
  const int l  = threadIdx.x & 63;
  const int h  = w >> 1;             // output half: waves 0,1 -> 0; waves 2,3 -> 1
  const int pg = w & 1;              // position group within block
  const int b  = blockIdx.x >> 6;    // 256 positions per block
  const int hw0 = ((blockIdx.x & 63) << 8) + (pg << 7) + l;   // pos A; pos B = +64

  const float* xb  = x  + b*262144 + hw0;
  const float* mub = mu + b*2097152 + hw0;

  // ---- load x for both positions ----
  float xv0[16], xv1[16];
  #pragma unroll
  for (int c = 0; c < 16; ++c){ xv0[c] = xb[c*HWN]; xv1[c] = xb[c*HWN + 64]; }

  // ---- init accumulators (64 outputs per position): bias + x-part ----
  const float* WmuT = ws + WS_WMUT;
  const float* bmu  = ws + WS_BMU;
  v2f aA[32], aB[32];
  #pragma unroll
  for (int j = 0; j < 32; ++j){
    v2f bb; bb.x = bmu[h*64 + 2*j]; bb.y = bmu[h*64 + 2*j + 1];
    aA[j] = bb; aB[j] = bb;
  }
  #pragma unroll
  for (int c = 0; c < 16; ++c){
    const v2f* wr = (const v2f*)(WmuT + c*128 + h*64);
    v2f vA; vA.x = xv0[c]; vA.y = xv0[c];
    v2f vB; vB.x = xv1[c]; vB.y = xv1[c];
    #pragma unroll
    for (int j = 0; j < 32; ++j){ aA[j] = pkfma(wr[j], vA, aA[j]); aB[j] = pkfma(wr[j], vB, aB[j]); }
  }

  // ---- sigma base accumulators: bias + x-part ----
  const float* WsigT = ws + WS_WSIGT;
  float sbA[8], sbB[8];
  #pragma unroll
  for (int jj = 0; jj < 8; ++jj){ sbA[jj] = (ws + WS_BSIG)[jj]; sbB[jj] = sbA[jj]; }
  #pragma unroll
  for (int c = 0; c < 16; ++c){
    #pragma unroll
    for (int jj = 0; jj < 8; ++jj){
      float wv = WsigT[c*8 + jj];
      sbA[jj] = __builtin_fmaf(wv, xv0[c], sbA[jj]);
      sbB[jj] = __builtin_fmaf(wv, xv1[c], sbB[jj]);
    }
  }

  // ---- pi logits (accumulated incrementally in the k-loop) ----
  const float* Wpi = ws + WS_WPI;
  float logitA[8], logitB[8];
  #pragma unroll
  for (int j = 0; j < 8; ++j){ logitA[j] = (ws + WS_BPI)[j]; logitB[j] = logitA[j]; }

  // ---- rolled k-loop: stream mu once; dist1 -> dens -> alpha/rho folded in ----
  #pragma unroll 1
  for (int k = 0; k < 8; ++k){
    const float* mrow = mub + (k*16)*HWN;
    const v2f*   wk   = (const v2f*)(WmuT + (16 + k*16)*128 + h*64);

    float dA = 0.f, dB = 0.f;
    #pragma unroll
    for (int cg = 0; cg < 4; ++cg){
      float mA[4], mB[4];
      #pragma unroll
      for (int u = 0; u < 4; ++u){
        mA[u] = mrow[(cg*4 + u)*HWN];
        mB[u] = mrow[(cg*4 + u)*HWN + 64];
      }
      #pragma unroll
      for (int u = 0; u < 4; ++u){
        const int c = cg*4 + u;
        float tA = xv0[c] - mA[u]; dA = __builtin_fmaf(tA, tA, dA);
        float tB = xv1[c] - mB[u]; dB = __builtin_fmaf(tB, tB, dB);
        v2f vA; vA.x = mA[u]; vA.y = mA[u];
        v2f vB; vB.x = mB[u]; vB.y = mB[u];
        const v2f* wr = wk + c*64;
        #pragma unroll
        for (int j = 0; j < 32; ++j){ aA[j] = pkfma(wr[j], vA, aA[j]); aB[j] = pkfma(wr[j], vB, aB[j]); }
      }
    }

    // per-component tail: density, alpha, rho
    float piA = pi[b*131072 + k*HWN + hw0];
    float piB = pi[b*131072 + k*HWN + hw0 + 64];
    float sgA = sigma[b*131072 + k*HWN + hw0];
    float sgB = sigma[b*131072 + k*HWN + hw0 + 64];
    float s2A = sgA*sgA, s2B = sgB*sgB;
    float p1A = 6.2831853071795864f * s2A; float p2A = p1A*p1A, p4A = p2A*p2A, p8A = p4A*p4A;
    float p1B = 6.2831853071795864f * s2B; float p2B = p1B*p1B, p4B = p2B*p2B, p8B = p4B*p4B;
    float densA = __expf(-0.5f * dA / s2A) / p8A;
    float densB = __expf(-0.5f * dB / s2B) / p8B;
    float alphaA = piA * densA, alphaB = piB * densB;
    float rhoA = alphaA * densA, rhoB = alphaB * densB;

    // pi logits: column k (pi) and column 8+k (alpha)
    #pragma unroll
    for (int j = 0; j < 8; ++j){
      logitA[j] = __builtin_fmaf(Wpi[j*16 + k],     piA,    logitA[j]);
      logitA[j] = __builtin_fmaf(Wpi[j*16 + 8 + k], alphaA, logitA[j]);
      logitB[j] = __builtin_fmaf(Wpi[j*16 + k],     piB,    logitB[j]);
      logitB[j] = __builtin_fmaf(Wpi[j*16 + 8 + k], alphaB, logitB[j]);
    }

    // rho contribution: matvec row 144+k, sigma row 144+k
    {
      const v2f* wr = (const v2f*)(WmuT + (144 + k)*128 + h*64);
      v2f vA; vA.x = rhoA; vA.y = rhoA;
      v2f vB; vB.x = rhoB; vB.y = rhoB;
      #pragma unroll
      for (int j = 0; j < 32; ++j){ aA[j] = pkfma(wr[j], vA, aA[j]); aB[j] = pkfma(wr[j], vB, aB[j]); }
      #pragma unroll
      for (int jj = 0; jj < 8; ++jj){
        float wv = WsigT[(144 + k)*8 + jj];
        sbA[jj] = __builtin_fmaf(wv, rhoA, sbA[jj]);
        sbB[jj] = __builtin_fmaf(wv, rhoB, sbB[jj]);
      }
    }
  }

  // ---- softmax -> pi_new (computed redundantly by both halves; h==0 stores) ----
  float pinA[8], pinB[8];
  {
    float mxA = -1e30f, mxB = -1e30f;
    #pragma unroll
    for (int j = 0; j < 8; ++j){ mxA = fmaxf(mxA, logitA[j]); mxB = fmaxf(mxB, logitB[j]); }
    float sA = 0.f, sB = 0.f;
    #pragma unroll
    for (int j = 0; j < 8; ++j){
      pinA[j] = __expf(logitA[j] - mxA); sA += pinA[j];
      pinB[j] = __expf(logitB[j] - mxB); sB += pinB[j];
    }
    float rA = 1.f / sA, rB = 1.f / sB;
    #pragma unroll
    for (int j = 0; j < 8; ++j){ pinA[j] *= rA; pinB[j] *= rB; }
  }
  if (h == 0){
    float* out_pi = out + b*131072 + hw0;
    #pragma unroll
    for (int j = 0; j < 8; ++j){
      __builtin_nontemporal_store(pinA[j], &out_pi[j*HWN]);
      __builtin_nontemporal_store(pinB[j], &out_pi[j*HWN + 64]);
    }
  }

  // ---- epilogue: relu, store mu_new (my 64 channels), dist2 (my 4 comps), sigma mu-part ----
  float* out_mu = out + 2097152 + b*2097152 + hw0;
  float d2A[4], d2B[4], smA[8], smB[8];
  #pragma unroll
  for (int i = 0; i < 4; ++i){ d2A[i] = 0.f; d2B[i] = 0.f; }
  #pragma unroll
  for (int jj = 0; jj < 8; ++jj){ smA[jj] = 0.f; smB[jj] = 0.f; }
  #pragma unroll
  for (int j = 0; j < 64; ++j){
    float rawA = (j & 1) ? aA[j>>1].y : aA[j>>1].x;
    float rawB = (j & 1) ? aB[j>>1].y : aB[j>>1].x;
    float mnA = fmaxf(rawA, 0.f);
    float mnB = fmaxf(rawB, 0.f);
    __builtin_nontemporal_store(mnA, &out_mu[(h*64 + j)*HWN]);
    __builtin_nontemporal_store(mnB, &out_mu[(h*64 + j)*HWN + 64]);
    float tA = xv0[j & 15] - mnA; d2A[j>>4] = __builtin_fmaf(tA, tA, d2A[j>>4]);
    float tB = xv1[j & 15] - mnB; d2B[j>>4] = __builtin_fmaf(tB, tB, d2B[j>>4]);
    #pragma unroll
    for (int jj = 0; jj < 8; ++jj){
      float wv = WsigT[(16 + h*64 + j)*8 + jj];
      smA[jj] = __builtin_fmaf(wv, mnA, smA[jj]);
      smB[jj] = __builtin_fmaf(wv, mnB, smB[jj]);
    }
  }

  // ---- exchange with partner wave (other output half, same positions) ----
  __shared__ float xch[2][2][64][25];   // [pg][h][lane][24 used + 1 pad]
  {
    float* mine = &xch[pg][h][l][0];
    #pragma unroll
    for (int jj = 0; jj < 8; ++jj) mine[jj] = smA[jj];
    #pragma unroll
    for (int i = 0; i < 4; ++i) mine[8 + i] = d2A[i];
    #pragma unroll
    for (int jj = 0; jj < 8; ++jj) mine[12 + jj] = smB[jj];
    #pragma unroll
    for (int i = 0; i < 4; ++i) mine[20 + i] = d2B[i];
  }
  __syncthreads();
  const float* oth = &xch[pg][h^1][l][0];

  // ---- sigma_new, dens2, gamma ----
  const float* Wg = ws + WS_WG;
  float* out_sig = out + 35651584 + b*131072 + hw0;
  float snA[8], snB[8];
  #pragma unroll
  for (int k = 0; k < 8; ++k){
    float sAk = sbA[k] + smA[k] + oth[k];
    float sBk = sbB[k] + smB[k] + oth[12 + k];
    snA[k] = __expf(fmaxf(sAk, 0.f));
    snB[k] = __expf(fmaxf(sBk, 0.f));
  }
  if (h == 0){
    #pragma unroll
    for (int k = 0; k < 4; ++k){
      __builtin_nontemporal_store(snA[k], &out_sig[k*HWN]);
      __builtin_nontemporal_store(snB[k], &out_sig[k*HWN + 64]);
    }
  } else {
    #pragma unroll
    for (int k = 4; k < 8; ++k){
      __builtin_nontemporal_store(snA[k], &out_sig[k*HWN]);
      __builtin_nontemporal_store(snB[k], &out_sig[k*HWN + 64]);
    }
  }

  float gA = ws[WS_BG], gB = gA;
  #pragma unroll
  for (int k = 0; k < 8; ++k){
    float dist2Ak = ((k >> 2) == h) ? d2A[k & 3] : oth[8 + (k & 3)];
    float dist2Bk = ((k >> 2) == h) ? d2B[k & 3] : oth[20 + (k & 3)];
    float s2A = snA[k]*snA[k];
    float s2B = snB[k]*snB[k];
    float p1A = 6.2831853071795864f * s2A; float p2A = p1A*p1A, p4A = p2A*p2A, p8A = p4A*p4A;
    float p1B = 6.2831853071795864f * s2B; float p2B = p1B*p1B, p4B = p2B*p2B, p8B = p4B*p4B;
    float dnA = __expf(-0.5f * dist2Ak / s2A) / p8A;
    float dnB = __expf(-0.5f * dist2Bk / s2B) / p8B;
    gA = __builtin_fmaf(Wg[k], pinA[k] * dnA, gA);
    gB = __builtin_fmaf(Wg[k], pinB[k] * dnB, gB);
  }
  if (h == 0){
    const int pA = blockIdx.x*256 + pg*128 + l;
    float gvA = 1.f / (1.f + __expf(-gA));
    float gvB = 1.f / (1.f + __expf(-gB));
    __builtin_nontemporal_store(gvA, &out[37748736 + pA]);
    __builtin_nontemporal_store(gvB, &out[37748736 + pA + 64]);
  }
}

extern "C" void kernel_launch(void* const* d_in, const int* in_sizes, int n_in,
                              void* d_out, int out_size, void* d_ws, size_t ws_size,
                              hipStream_t stream)
{
  const float* x    = (const float*)d_in[0];
  const float* pi   = (const float*)d_in[1];
  const float* mu   = (const float*)d_in[2];
  const float* sg   = (const float*)d_in[3];
  const float* Wpi  = (const float*)d_in[4];
  const float* bpi  = (const float*)d_in[5];
  const float* Wmu  = (const float*)d_in[6];
  const float* bmu  = (const float*)d_in[7];
  const float* Wsig = (const float*)d_in[8];
  const float* bsig = (const float*)d_in[9];
  const float* Wg   = (const float*)d_in[10];
  const float* bg   = (const float*)d_in[11];
  float* ws  = (float*)d_ws;
  float* out = (float*)d_out;

  prep_weights<<<(WS_TOTAL + 255)/256, 256, 0, stream>>>(
      Wpi, bpi, Wmu, bmu, Wsig, bsig, Wg, bg, ws);
  gmm_fused<<<NPOS/256, 256, 0, stream>>>(x, pi, sg, mu, ws, out);
}

// Round 5
// 530.582 us; speedup vs baseline: 1.6450x; 1.6450x over previous
//
#include <hip/hip_runtime.h>

#define NPOS (16*128*128)   // B*H*W = 262144
#define HWN  16384          // H*W

typedef float v2f __attribute__((ext_vector_type(2)));
typedef float v4f __attribute__((ext_vector_type(4)));

// workspace float offsets
#define WS_WMUT  0          // [152][128] transposed Wmu (row r = input channel, col o = output)
#define WS_WSIGT 19456      // [152][8]   transposed Wsig
#define WS_WPI   20672      // [8][16]
#define WS_BPI   20800      // [8]
#define WS_BMU   20808      // [128]
#define WS_BSIG  20936      // [8]
#define WS_WG    20944      // [8]
#define WS_BG    20952      // [1]
#define WS_TOTAL 20953

__global__ __launch_bounds__(256) void prep_weights(
    const float* __restrict__ Wpi, const float* __restrict__ bpi,
    const float* __restrict__ Wmu, const float* __restrict__ bmu,
    const float* __restrict__ Wsig, const float* __restrict__ bsig,
    const float* __restrict__ Wg,  const float* __restrict__ bg,
    float* __restrict__ ws)
{
  int i = blockIdx.x*256 + threadIdx.x;
  if (i < 19456){ int c = i >> 7, o = i & 127; ws[WS_WMUT + i] = Wmu[o*152 + c]; return; }
  i -= 19456;
  if (i < 1216){ int c = i >> 3, j = i & 7; ws[WS_WSIGT + i] = Wsig[j*152 + c]; return; }
  i -= 1216;
  if (i < 128){ ws[WS_WPI + i] = Wpi[i]; return; }
  i -= 128;
  if (i < 8){ ws[WS_BPI + i] = bpi[i]; return; }
  i -= 8;
  if (i < 128){ ws[WS_BMU + i] = bmu[i]; return; }
  i -= 128;
  if (i < 8){ ws[WS_BSIG + i] = bsig[i]; return; }
  i -= 8;
  if (i < 8){ ws[WS_WG + i] = Wg[i]; return; }
  i -= 8;
  if (i < 1){ ws[WS_BG] = bg[0]; }
}

__device__ __forceinline__ v2f pkfma(v2f a, v2f b, v2f c){
#if __has_builtin(__builtin_elementwise_fma)
  return __builtin_elementwise_fma(a, b, c);
#else
  v2f r; r.x = __builtin_fmaf(a.x, b.x, c.x); r.y = __builtin_fmaf(a.y, b.y, c.y); return r;
#endif
}

// Round-2 structure (1 position x 128 outputs/thread, no spill) + WmuT staged
// in LDS (77824 B <= 80 KB -> keeps 2 blocks/CU). Weight reads become
// ds_read_b128 broadcasts (uniform addr, conflict-free, lgkm-pipelined)
// instead of s_load streams that thrashed the scalar K$ (16 waves/CU x
// 77.8 KB >> 16 KB K$ -> ~200cy L2 hits on the scalar pipe = the round-2
// stall). k-loop rolled: ~10 KB body stays I$-resident. WsigT/Wpi/biases
// stay scalar -- 6 KB fits K$ once the Wmu stream is gone.
__global__ __launch_bounds__(256, 2) void gmm_fused(
    const float* __restrict__ x,
    const float* __restrict__ pi,
    const float* __restrict__ sigma,
    const float* __restrict__ mu,
    const float* __restrict__ ws,
    float* __restrict__ out)
{
  __shared__ float ldsw[19456];   // WmuT [152][128]

  const int tid = threadIdx.x;
  const int p  = blockIdx.x*256 + tid;
  const int b  = p >> 14;
  const int hw = p & (HWN-1);

  const float* xb  = x  + b*262144 + hw;   // [b][c][hw], c stride HWN
  const float* mub = mu + b*2097152 + hw;  // [b][m][hw], m stride HWN

  // ---- stage WmuT into LDS (19456 floats = 4864 float4 = 19 per thread) ----
  {
    const v4f* src = (const v4f*)(ws + WS_WMUT);
    v4f* dst = (v4f*)ldsw;
    #pragma unroll
    for (int i = 0; i < 19; ++i) dst[tid + i*256] = src[tid + i*256];
  }

  // ---- load x (overlaps staging) ----
  float xv[16];
  #pragma unroll
  for (int c = 0; c < 16; ++c) xv[c] = xb[c*HWN];

  __syncthreads();

  // ---- init mu_new accumulators: bias + x-part (weights from LDS) ----
  const float* bmu = ws + WS_BMU;
  v2f a2[64];
  #pragma unroll
  for (int j = 0; j < 64; ++j){ a2[j].x = bmu[2*j]; a2[j].y = bmu[2*j+1]; }
  #pragma unroll
  for (int c = 0; c < 16; ++c){
    v2f vv; vv.x = xv[c]; vv.y = xv[c];
    const v4f* w4 = (const v4f*)(ldsw + c*128);
    #pragma unroll
    for (int j = 0; j < 32; ++j){
      v4f w = w4[j];
      v2f lo = __builtin_shufflevector(w, w, 0, 1);
      v2f hi = __builtin_shufflevector(w, w, 2, 3);
      a2[2*j]   = pkfma(lo, vv, a2[2*j]);
      a2[2*j+1] = pkfma(hi, vv, a2[2*j+1]);
    }
  }

  // ---- sigma base accumulators: bias + x-part (scalar WsigT: 6 KB, K$-resident) ----
  const float* WsigT = ws + WS_WSIGT;
  float sacc[8];
  #pragma unroll
  for (int jj = 0; jj < 8; ++jj) sacc[jj] = (ws + WS_BSIG)[jj];
  #pragma unroll
  for (int c = 0; c < 16; ++c){
    float v = xv[c];
    #pragma unroll
    for (int jj = 0; jj < 8; ++jj) sacc[jj] = __builtin_fmaf(WsigT[c*8 + jj], v, sacc[jj]);
  }

  // ---- pi logits accumulated incrementally ----
  const float* Wpi = ws + WS_WPI;
  float logit[8];
  #pragma unroll
  for (int j = 0; j < 8; ++j) logit[j] = (ws + WS_BPI)[j];

  // ---- rolled k-loop: stream mu once; dist1 -> dens -> alpha/rho folded in ----
  #pragma unroll 1
  for (int k = 0; k < 8; ++k){
    const float* mrow = mub + (k*16)*HWN;

    // issue all 16 mu loads + the pi/sigma loads for this k up front;
    // ~2k cycles of FMA below covers the latency
    float mv[16];
    #pragma unroll
    for (int c = 0; c < 16; ++c) mv[c] = mrow[c*HWN];
    float pik = pi[b*131072 + k*HWN + hw];
    float sgk = sigma[b*131072 + k*HWN + hw];

    float d = 0.f;
    #pragma unroll
    for (int c = 0; c < 16; ++c){
      float t = xv[c] - mv[c];
      d = __builtin_fmaf(t, t, d);
      v2f vv; vv.x = mv[c]; vv.y = mv[c];
      const v4f* w4 = (const v4f*)(ldsw + (16 + k*16 + c)*128);
      #pragma unroll
      for (int j = 0; j < 32; ++j){
        v4f w = w4[j];
        v2f lo = __builtin_shufflevector(w, w, 0, 1);
        v2f hi = __builtin_shufflevector(w, w, 2, 3);
        a2[2*j]   = pkfma(lo, vv, a2[2*j]);
        a2[2*j+1] = pkfma(hi, vv, a2[2*j+1]);
      }
    }

    // density, alpha, rho
    float s2 = sgk*sgk;
    float p1 = 6.2831853071795864f * s2;
    float p2 = p1*p1, p4 = p2*p2, p8 = p4*p4;
    float dens = __expf(-0.5f * d / s2) / p8;
    float alpha = pik * dens;
    float rho   = alpha * dens;

    // pi logits: column k (pi) and 8+k (alpha)
    #pragma unroll
    for (int j = 0; j < 8; ++j){
      logit[j] = __builtin_fmaf(Wpi[j*16 + k],     pik,   logit[j]);
      logit[j] = __builtin_fmaf(Wpi[j*16 + 8 + k], alpha, logit[j]);
    }

    // rho contribution: matvec row 144+k (LDS), sigma row 144+k (scalar)
    {
      v2f vv; vv.x = rho; vv.y = rho;
      const v4f* w4 = (const v4f*)(ldsw + (144 + k)*128);
      #pragma unroll
      for (int j = 0; j < 32; ++j){
        v4f w = w4[j];
        v2f lo = __builtin_shufflevector(w, w, 0, 1);
        v2f hi = __builtin_shufflevector(w, w, 2, 3);
        a2[2*j]   = pkfma(lo, vv, a2[2*j]);
        a2[2*j+1] = pkfma(hi, vv, a2[2*j+1]);
      }
      #pragma unroll
      for (int jj = 0; jj < 8; ++jj)
        sacc[jj] = __builtin_fmaf(WsigT[(144 + k)*8 + jj], rho, sacc[jj]);
    }
  }

  // ---- softmax -> pi_new ----
  float pin[8], mx = -1e30f;
  #pragma unroll
  for (int j = 0; j < 8; ++j) mx = fmaxf(mx, logit[j]);
  float ssum = 0.f;
  #pragma unroll
  for (int j = 0; j < 8; ++j){ pin[j] = __expf(logit[j] - mx); ssum += pin[j]; }
  float rs = 1.f / ssum;
  float* out_pi = out + b*131072 + hw;
  #pragma unroll
  for (int j = 0; j < 8; ++j){
    pin[j] *= rs;
    __builtin_nontemporal_store(pin[j], &out_pi[j*HWN]);
  }

  // ---- epilogue: relu, store mu_new, dist2, sigma accumulation ----
  float* out_mu = out + 2097152 + b*2097152 + hw;
  float dist2v[8];
  #pragma unroll
  for (int k = 0; k < 8; ++k) dist2v[k] = 0.f;
  #pragma unroll
  for (int j = 0; j < 128; ++j){
    float raw = (j & 1) ? a2[j>>1].y : a2[j>>1].x;
    float mn = fmaxf(raw, 0.f);
    __builtin_nontemporal_store(mn, &out_mu[j*HWN]);
    float t = xv[j & 15] - mn;
    dist2v[j>>4] = __builtin_fmaf(t, t, dist2v[j>>4]);
    #pragma unroll
    for (int jj = 0; jj < 8; ++jj)
      sacc[jj] = __builtin_fmaf(WsigT[(16 + j)*8 + jj], mn, sacc[jj]);
  }

  // ---- sigma_new, dens2, gamma ----
  const float* Wg = ws + WS_WG;
  float g = ws[WS_BG];
  float* out_sig = out + 35651584 + b*131072 + hw;
  #pragma unroll
  for (int k = 0; k < 8; ++k){
    float sn = __expf(fmaxf(sacc[k], 0.f));
    __builtin_nontemporal_store(sn, &out_sig[k*HWN]);
    float s2 = sn*sn;
    float p1 = 6.2831853071795864f * s2;
    float p2 = p1*p1, p4 = p2*p2, p8 = p4*p4;
    float dn2 = __expf(-0.5f * dist2v[k] / s2) / p8;
    g = __builtin_fmaf(Wg[k], pin[k] * dn2, g);
  }
  float gv = 1.f / (1.f + __expf(-g));
  __builtin_nontemporal_store(gv, &out[37748736 + p]);
}

extern "C" void kernel_launch(void* const* d_in, const int* in_sizes, int n_in,
                              void* d_out, int out_size, void* d_ws, size_t ws_size,
                              hipStream_t stream)
{
  const float* x    = (const float*)d_in[0];
  const float* pi   = (const float*)d_in[1];
  const float* mu   = (const float*)d_in[2];
  const float* sg   = (const float*)d_in[3];
  const float* Wpi  = (const float*)d_in[4];
  const float* bpi  = (const float*)d_in[5];
  const float* Wmu  = (const float*)d_in[6];
  const float* bmu  = (const float*)d_in[7];
  const float* Wsig = (const float*)d_in[8];
  const float* bsig = (const float*)d_in[9];
  const float* Wg   = (const float*)d_in[10];
  const float* bg   = (const float*)d_in[11];
  float* ws  = (float*)d_ws;
  float* out = (float*)d_out;

  prep_weights<<<(WS_TOTAL + 255)/256, 256, 0, stream>>>(
      Wpi, bpi, Wmu, bmu, Wsig, bsig, Wg, bg, ws);
  gmm_fused<<<NPOS/256, 256, 0, stream>>>(x, pi, sg, mu, ws, out);
}

// Round 7
// 307.993 us; speedup vs baseline: 2.8339x; 1.7227x over previous
//
#include <hip/hip_runtime.h>

#define NPOS (16*128*128)   // B*H*W = 262144
#define HWN  16384          // H*W

typedef float v4f __attribute__((ext_vector_type(4)));
typedef _Float16 h8 __attribute__((ext_vector_type(8)));

// workspace float offsets
#define WS_B     0          // fp16 B-fragments: 8n x 5s x 512 halves = 20480 halves = 10240 float slots
#define WS_WSIGT 19456      // [152][8] transposed Wsig (f32)
#define WS_WPI   20672      // [8][16]
#define WS_BPI   20800      // [8]
#define WS_BMU   20808      // [128]
#define WS_BSIG  20936      // [8]
#define WS_WG    20944      // [8]
#define WS_BG    20952      // [1]
#define WS_TOTAL 20953

__global__ __launch_bounds__(256) void prep_weights(
    const float* __restrict__ Wpi, const float* __restrict__ bpi,
    const float* __restrict__ Wmu, const float* __restrict__ bmu,
    const float* __restrict__ Wsig, const float* __restrict__ bsig,
    const float* __restrict__ Wg,  const float* __restrict__ bg,
    float* __restrict__ ws)
{
  int i = blockIdx.x*256 + threadIdx.x;
  // B-fragments for mfma_f32_16x16x32_f16: block (n,s) holds 64 lanes x 8 halves,
  // lane l gets out = 16n + (l&15), k = 32s + 8*(l>>4) + j  (k>=152 -> 0)
  if (i < 20480){
    int j = i & 7, lq = (i >> 3) & 63, blk = i >> 9;
    int s = blk % 5, n = blk / 5;
    int o = 16*n + (lq & 15);
    int r = 32*s + 8*(lq >> 4) + j;
    float v = (r < 152) ? Wmu[o*152 + r] : 0.f;
    ((_Float16*)ws)[i] = (_Float16)v;
    return;
  }
  i -= 20480;
  if (i < 1216){ int c = i >> 3, j = i & 7; ws[WS_WSIGT + i] = Wsig[j*152 + c]; return; }
  i -= 1216;
  if (i < 128){ ws[WS_WPI + i] = Wpi[i]; return; }
  i -= 128;
  if (i < 8){ ws[WS_BPI + i] = bpi[i]; return; }
  i -= 8;
  if (i < 128){ ws[WS_BMU + i] = bmu[i]; return; }
  i -= 128;
  if (i < 8){ ws[WS_BSIG + i] = bsig[i]; return; }
  i -= 8;
  if (i < 8){ ws[WS_WG + i] = Wg[i]; return; }
  i -= 8;
  if (i < 1){ ws[WS_BG] = bg[0]; }
}

// MFMA-based: the 152x128 matvec is a GEMM C[pos,out] = In[pos,152] x W[152,128]
// done with mfma_f32_16x16x32_f16. Per wave = 64 positions (lane = position in
// phase 1, identical per-position code to the 315us round-2 kernel). Weights are
// per-lane register fragments: 40 coalesced b128 loads/wave-pass instead of the
// ~4.9k uniform b128 loads that made s_load (r2) and ds_read (r5) delivery the
// bottleneck. A-frags (80 VGPR) built via a wave-private 5KB LDS slice buffer;
// C tiles transient (16 VGPR) -> no spill. fp16 err ~3e-4 << absmax margin.
__global__ __launch_bounds__(256, 2) void gmm_fused(
    const float* __restrict__ x,
    const float* __restrict__ pi,
    const float* __restrict__ sigma,
    const float* __restrict__ mu,
    const float* __restrict__ ws,
    float* __restrict__ out)
{
  __shared__ v4f ldsraw[4][320];   // 5120 B per wave

  const int tid = threadIdx.x;
  const int w = tid >> 6, l = tid & 63;
  const int p  = blockIdx.x*256 + tid;
  const int b  = p >> 14;
  const int hw = p & (HWN-1);

  const float* xb  = x  + b*262144 + hw;
  const float* mub = mu + b*2097152 + hw;

  _Float16* slc = (_Float16*)ldsraw[w];  // [64][40] halves (32 used + 8 pad)
  float*    trp = (float*)ldsraw[w];     // [16][68] f32 transpose buffer

  // ---- x and pi/sigma upfront ----
  float xv[16];
  #pragma unroll
  for (int c = 0; c < 16; ++c) xv[c] = xb[c*HWN];
  float piv[8], s2v[8];
  #pragma unroll
  for (int k = 0; k < 8; ++k){
    piv[k] = pi[b*131072 + k*HWN + hw];
    float s = sigma[b*131072 + k*HWN + hw];
    s2v[k] = s*s;
  }

  const float* WsigT = ws + WS_WSIGT;
  const float* Wpi   = ws + WS_WPI;

  float logit[8];
  #pragma unroll
  for (int j = 0; j < 8; ++j) logit[j] = (ws + WS_BPI)[j];
  float sacc[8];
  #pragma unroll
  for (int jj = 0; jj < 8; ++jj) sacc[jj] = (ws + WS_BSIG)[jj];
  #pragma unroll
  for (int c = 0; c < 16; ++c){
    float v = xv[c];
    #pragma unroll
    for (int jj = 0; jj < 8; ++jj) sacc[jj] = __builtin_fmaf(WsigT[c*8 + jj], v, sacc[jj]);
  }
  float rhov[8];
  h8 A[4][5];   // A-fragments [M-tile][k-slice], all indices static

#define LOADMU(MV, K) do { const float* _mr = mub + (K)*16*HWN; \
  _Pragma("unroll") for (int c = 0; c < 16; ++c) (MV)[c] = _mr[c*HWN]; } while(0)

#define PROC_COMP(K, MV, OFF) do { \
  float _d = 0.f; \
  _Pragma("unroll") for (int c = 0; c < 16; ++c){ float _t = xv[c] - (MV)[c]; _d = __builtin_fmaf(_t,_t,_d); } \
  h8 _ha, _hb; \
  _Pragma("unroll") for (int j = 0; j < 8; ++j){ _ha[j] = (_Float16)(MV)[j]; _hb[j] = (_Float16)(MV)[8+j]; } \
  *(h8*)(slc + l*40 + (OFF))     = _ha; \
  *(h8*)(slc + l*40 + (OFF) + 8) = _hb; \
  float _s2 = s2v[(K)]; \
  float _p1 = 6.2831853071795864f * _s2; float _p2 = _p1*_p1, _p4 = _p2*_p2, _p8 = _p4*_p4; \
  float _dens = __expf(-0.5f * _d / _s2) / _p8; \
  float _alpha = piv[(K)] * _dens; rhov[(K)] = _alpha * _dens; \
  _Pragma("unroll") for (int j = 0; j < 8; ++j){ \
    logit[j] = __builtin_fmaf(Wpi[j*16 + (K)],     piv[(K)], logit[j]); \
    logit[j] = __builtin_fmaf(Wpi[j*16 + 8 + (K)], _alpha,   logit[j]); } \
} while(0)

#define AREAD(S) do { \
  _Pragma("unroll") for (int m = 0; m < 4; ++m) \
    A[m][(S)] = *(const h8*)(slc + (16*m + (l & 15))*40 + (l >> 4)*8); \
} while(0)

  float mva[16], mvb[16];

  // ---- phase 1: stream mu once; per k-slice: stage fp16 In, grab A-frags ----
  LOADMU(mva, 0);
  {  // x -> slice 0 lower half
    h8 h0, h1;
    #pragma unroll
    for (int j = 0; j < 8; ++j){ h0[j] = (_Float16)xv[j]; h1[j] = (_Float16)xv[8+j]; }
    *(h8*)(slc + l*40)     = h0;
    *(h8*)(slc + l*40 + 8) = h1;
  }
  LOADMU(mvb, 1);                 // prefetch comp 1
  PROC_COMP(0, mva, 16);
  AREAD(0);
  LOADMU(mva, 2);
  PROC_COMP(1, mvb, 0);
  LOADMU(mvb, 3);
  PROC_COMP(2, mva, 16);
  AREAD(1);
  LOADMU(mva, 4);
  PROC_COMP(3, mvb, 0);
  LOADMU(mvb, 5);
  PROC_COMP(4, mva, 16);
  AREAD(2);
  LOADMU(mva, 6);
  PROC_COMP(5, mvb, 0);
  LOADMU(mvb, 7);
  PROC_COMP(6, mva, 16);
  AREAD(3);
  PROC_COMP(7, mvb, 0);
  {  // rho rows + zero pad -> slice 4 upper half
    h8 hr, hz;
    #pragma unroll
    for (int j = 0; j < 8; ++j){ hr[j] = (_Float16)rhov[j]; hz[j] = (_Float16)0.f; }
    *(h8*)(slc + l*40 + 16) = hr;
    *(h8*)(slc + l*40 + 24) = hz;
  }
  AREAD(4);

  // ---- softmax -> pi_new ----
  float pin[8], mx = -1e30f;
  #pragma unroll
  for (int j = 0; j < 8; ++j) mx = fmaxf(mx, logit[j]);
  float ssum = 0.f;
  #pragma unroll
  for (int j = 0; j < 8; ++j){ pin[j] = __expf(logit[j] - mx); ssum += pin[j]; }
  float rs = 1.f / ssum;
  float* out_pi = out + b*131072 + hw;
  #pragma unroll
  for (int j = 0; j < 8; ++j){
    pin[j] *= rs;
    __builtin_nontemporal_store(pin[j], &out_pi[j*HWN]);
  }

  // ---- phase 2: MFMA GEMM, one N-tile (= one component) at a time ----
  const _Float16* Bp  = (const _Float16*)ws;
  const float*    bmu = ws + WS_BMU;
  float* out_mu = out + 2097152 + b*2097152 + hw;
  float dist2v[8];

  #pragma unroll
  for (int n = 0; n < 8; ++n){
    h8 Bf[5];
    #pragma unroll
    for (int s = 0; s < 5; ++s)
      Bf[s] = *(const h8*)(Bp + (n*5 + s)*512 + l*8);
    float bias = bmu[16*n + (l & 15)];
    v4f C[4];
    #pragma unroll
    for (int m = 0; m < 4; ++m){ C[m][0] = bias; C[m][1] = bias; C[m][2] = bias; C[m][3] = bias; }
    #pragma unroll
    for (int s = 0; s < 5; ++s){
      #pragma unroll
      for (int m = 0; m < 4; ++m)
        C[m] = __builtin_amdgcn_mfma_f32_16x16x32_f16(A[m][s], Bf[s], C[m], 0, 0, 0);
    }
    // relu in-reg, transpose via LDS: write [out=l&15][pos=16m+4*(l>>4)+j]
    #pragma unroll
    for (int m = 0; m < 4; ++m){
      #pragma unroll
      for (int j = 0; j < 4; ++j) C[m][j] = fmaxf(C[m][j], 0.f);
      *(v4f*)(trp + (l & 15)*68 + 16*m + 4*(l >> 4)) = C[m];
    }
    // each lane reads its own position's 16 channels of this component
    float d2 = 0.f;
    #pragma unroll
    for (int c = 0; c < 16; ++c){
      float mn = trp[c*68 + l];
      __builtin_nontemporal_store(mn, &out_mu[(16*n + c)*HWN]);
      float t = xv[c] - mn;
      d2 = __builtin_fmaf(t, t, d2);
      #pragma unroll
      for (int jj = 0; jj < 8; ++jj)
        sacc[jj] = __builtin_fmaf(WsigT[(16 + 16*n + c)*8 + jj], mn, sacc[jj]);
    }
    dist2v[n] = d2;
  }

  // ---- sigma_new, dens2, gamma ----
  const float* Wg = ws + WS_WG;
  float g = ws[WS_BG];
  float* out_sig = out + 35651584 + b*131072 + hw;
  #pragma unroll
  for (int k = 0; k < 8; ++k){
    float sn = __expf(fmaxf(sacc[k], 0.f));
    __builtin_nontemporal_store(sn, &out_sig[k*HWN]);
    float s2 = sn*sn;
    float p1 = 6.2831853071795864f * s2;
    float p2 = p1*p1, p4 = p2*p2, p8 = p4*p4;
    float dn2 = __expf(-0.5f * dist2v[k] / s2) / p8;
    g = __builtin_fmaf(Wg[k], pin[k] * dn2, g);
  }
  float gv = 1.f / (1.f + __expf(-g));
  __builtin_nontemporal_store(gv, &out[37748736 + p]);
}

extern "C" void kernel_launch(void* const* d_in, const int* in_sizes, int n_in,
                              void* d_out, int out_size, void* d_ws, size_t ws_size,
                              hipStream_t stream)
{
  const float* x    = (const float*)d_in[0];
  const float* pi   = (const float*)d_in[1];
  const float* mu   = (const float*)d_in[2];
  const float* sg   = (const float*)d_in[3];
  const float* Wpi  = (const float*)d_in[4];
  const float* bpi  = (const float*)d_in[5];
  const float* Wmu  = (const float*)d_in[6];
  const float* bmu  = (const float*)d_in[7];
  const float* Wsig = (const float*)d_in[8];
  const float* bsig = (const float*)d_in[9];
  const float* Wg   = (const float*)d_in[10];
  const float* bg   = (const float*)d_in[11];
  float* ws  = (float*)d_ws;
  float* out = (float*)d_out;

  prep_weights<<<(20480 + 1497 + 255)/256, 256, 0, stream>>>(
      Wpi, bpi, Wmu, bmu, Wsig, bsig, Wg, bg, ws);
  gmm_fused<<<NPOS/256, 256, 0, stream>>>(x, pi, sg, mu, ws, out);
}